// Round 7
// baseline (1703.910 us; speedup 1.0000x reference)
//
#include <hip/hip_runtime.h>

#define S_LEN 4096
#define BATCH 4
#define NROWS 16384   // S*B
#define DIM   1024
#define CHUNK 32
#define NCHUNK (S_LEN / CHUNK)

typedef __attribute__((ext_vector_type(8))) short short8;
typedef __attribute__((ext_vector_type(4))) float floatx4;
typedef _Float16 half_t;
typedef __attribute__((ext_vector_type(8))) _Float16 half8;

__device__ __forceinline__ float bf2f(short s) {
    union { unsigned int u; float f; } c;
    c.u = ((unsigned int)(unsigned short)s) << 16;
    return c.f;
}
__device__ __forceinline__ short f2bf(float f) {
    union { float f; unsigned int u; } c; c.f = f;
    unsigned int r = c.u + 0x7fffu + ((c.u >> 16) & 1u);
    return (short)(r >> 16);
}
// split fp32 -> bf16 hi + bf16 lo (a ~= hi + lo, rel err ~2^-16)
__device__ __forceinline__ void split_bf16(float x, short& hi, short& lo) {
    short h = f2bf(x);
    hi = h;
    lo = f2bf(x - bf2f(h));
}

// 16-lane (DPP row) all-reduce sum: quad_perm xor1, xor2, row_ror:4, row_ror:8.
__device__ __forceinline__ float row16_allreduce(float x) {
    union fi { float f; int i; };
    fi a, b;
    a.f = x;
    b.i = __builtin_amdgcn_update_dpp(0, a.i, 0xB1,  0xF, 0xF, true); a.f += b.f; // xor1
    b.i = __builtin_amdgcn_update_dpp(0, a.i, 0x4E,  0xF, 0xF, true); a.f += b.f; // xor2
    b.i = __builtin_amdgcn_update_dpp(0, a.i, 0x124, 0xF, 0xF, true); a.f += b.f; // ror4
    b.i = __builtin_amdgcn_update_dpp(0, a.i, 0x128, 0xF, 0xF, true); a.f += b.f; // ror8
    return a.f;
}

// W[K][N] fp32 row-major -> Wt[N][K]
__global__ __launch_bounds__(256) void transpose_k(const float* __restrict__ W,
                                                   float* __restrict__ Wt,
                                                   int K, int N) {
    int idx = blockIdx.x * 256 + threadIdx.x;
    if (idx >= N * K) return;
    int n = idx / K;
    int k = idx - n * K;
    Wt[idx] = W[k * N + n];
}

// C = A[M,K] @ Bt[N,K]^T. A fp32 or fp16, Bt fp32. Split-bf16 3-term MFMA, fp32 acc.
// MODE 0: fp32 out at row*N+col (+ optional fp32 bias)
// MODE 1: fp16 out at row*2048 + (col>>6)*128 + (col&63)   (dpfp staging layout)
template <typename AT, int MODE>
__global__ __launch_bounds__(256) void gemm_bt(const AT* __restrict__ A,
                                               const float* __restrict__ Bt,
                                               void* __restrict__ Cout,
                                               const float* __restrict__ bias,
                                               int N, int K) {
    __shared__ __align__(16) short As_h[64][40], As_l[64][40];
    __shared__ __align__(16) short Bs_h[64][40], Bs_l[64][40];
    const int tid  = threadIdx.x;
    const int wave = tid >> 6, lane = tid & 63;
    const int row0 = blockIdx.x * 64, col0 = blockIdx.y * 64;
    const int lr = tid >> 2, lc = (tid & 3) * 8;   // staging: 64 rows x 4 groups of 8
    const AT*    Ap = A  + (size_t)(row0 + lr) * K + lc;
    const float* Bp = Bt + (size_t)(col0 + lr) * K + lc;
    const int am = wave * 16 + (lane & 15);        // A-frag row
    const int ak = (lane >> 4) * 8;                // k-slice start
    floatx4 acc[4];
    #pragma unroll
    for (int t = 0; t < 4; ++t) acc[t] = (floatx4){0.f, 0.f, 0.f, 0.f};

    for (int k0 = 0; k0 < K; k0 += 32) {
        float av[8], bv[8];
        if constexpr (sizeof(AT) == 4) {
            floatx4 a0 = *(const floatx4*)(Ap + k0);
            floatx4 a1 = *(const floatx4*)(Ap + k0 + 4);
            #pragma unroll
            for (int j = 0; j < 4; ++j) { av[j] = a0[j]; av[4 + j] = a1[j]; }
        } else {
            half8 a = *(const half8*)(Ap + k0);
            #pragma unroll
            for (int j = 0; j < 8; ++j) av[j] = (float)a[j];
        }
        floatx4 b0 = *(const floatx4*)(Bp + k0);
        floatx4 b1 = *(const floatx4*)(Bp + k0 + 4);
        #pragma unroll
        for (int j = 0; j < 4; ++j) { bv[j] = b0[j]; bv[4 + j] = b1[j]; }

        short8 ah, al, bh, bl;
        #pragma unroll
        for (int j = 0; j < 8; ++j) {
            short h, l;
            split_bf16(av[j], h, l); ah[j] = h; al[j] = l;
            split_bf16(bv[j], h, l); bh[j] = h; bl[j] = l;
        }
        *(short8*)&As_h[lr][lc] = ah;
        *(short8*)&As_l[lr][lc] = al;
        *(short8*)&Bs_h[lr][lc] = bh;
        *(short8*)&Bs_l[lr][lc] = bl;
        __syncthreads();
        short8 afh = *(const short8*)&As_h[am][ak];
        short8 afl = *(const short8*)&As_l[am][ak];
        #pragma unroll
        for (int t = 0; t < 4; ++t) {
            short8 bfh = *(const short8*)&Bs_h[t * 16 + (lane & 15)][ak];
            short8 bfl = *(const short8*)&Bs_l[t * 16 + (lane & 15)][ak];
            acc[t] = __builtin_amdgcn_mfma_f32_16x16x32_bf16(afh, bfh, acc[t], 0, 0, 0);
            acc[t] = __builtin_amdgcn_mfma_f32_16x16x32_bf16(afh, bfl, acc[t], 0, 0, 0);
            acc[t] = __builtin_amdgcn_mfma_f32_16x16x32_bf16(afl, bfh, acc[t], 0, 0, 0);
        }
        __syncthreads();
    }
    // C/D layout (verified m89/m91): col = lane&15, row = (lane>>4)*4 + reg
    const int crow = row0 + wave * 16 + (lane >> 4) * 4;
    const int ccol = lane & 15;
    #pragma unroll
    for (int t = 0; t < 4; ++t) {
        int col = col0 + t * 16 + ccol;
        #pragma unroll
        for (int r = 0; r < 4; ++r) {
            int row = crow + r;
            float v = acc[t][r];
            if (MODE == 0) {
                float b = bias ? bias[col] : 0.f;
                ((float*)Cout)[(size_t)row * N + col] = v + b;
            } else {
                ((half_t*)Cout)[(size_t)row * 2048 + (col >> 6) * 128 + (col & 63)] = (half_t)v;
            }
        }
    }
}

// beta = sigmoid(x @ Wb); one wave per row, Wbt fp32 [16][1024]
__global__ __launch_bounds__(256) void beta_kernel(const float* __restrict__ X,
                                                   const float* __restrict__ Wbt,
                                                   float* __restrict__ Beta) {
    int wid  = (blockIdx.x * 256 + threadIdx.x) >> 6;
    int lane = threadIdx.x & 63;
    if (wid >= NROWS) return;
    const float* xr = X + (size_t)wid * DIM + lane * 16;
    float xv[16];
    #pragma unroll
    for (int j = 0; j < 4; ++j) {
        floatx4 v = *(const floatx4*)(xr + j * 4);
        #pragma unroll
        for (int e = 0; e < 4; ++e) xv[j * 4 + e] = v[e];
    }
    #pragma unroll 1
    for (int h = 0; h < 16; ++h) {
        const float* wr = Wbt + h * DIM + lane * 16;
        float s = 0.f;
        #pragma unroll
        for (int j = 0; j < 4; ++j) {
            floatx4 v = *(const floatx4*)(wr + j * 4);
            #pragma unroll
            for (int e = 0; e < 4; ++e) s = fmaf(xv[j * 4 + e], v[e], s);
        }
        #pragma unroll
        for (int off = 32; off; off >>= 1) s += __shfl_xor(s, off);
        if (lane == 0) Beta[wid * 16 + h] = 1.f / (1.f + __expf(-s));
    }
}

// In-place DPFP on fp16 spans of 128 (first 64 hold raw p, written by gemm MODE 1).
__global__ __launch_bounds__(256) void dpfp_h(half_t* __restrict__ P) {
    int gw   = (blockIdx.x * 256 + threadIdx.x) >> 6;
    int lane = threadIdx.x & 63;
    half_t* base = P + (size_t)gw * 128;
    float p  = (float)base[lane];
    float pm = __shfl(p, (lane + 63) & 63);           // p[lane-1], lane0 gets p[63]
    float rp  = fmaxf(p, 0.f),  rn  = fmaxf(-p, 0.f);
    float rpm = fmaxf(pm, 0.f), rnm = fmaxf(-pm, 0.f);
    float aprev = (lane == 0) ? rnm : rpm;            // xc[(lane-1)%128]
    float bprev = (lane == 0) ? rpm : rnm;            // xc[lane+63]
    float phi_a = rp * aprev;                         // phi[lane]
    float phi_b = rn * bprev;                         // phi[lane+64]
    float s = phi_a + phi_b;
    #pragma unroll
    for (int off = 32; off; off >>= 1) s += __shfl_xor(s, off);
    float inv = 1.f / (s + 1e-6f);
    base[lane]      = (half_t)(phi_a * inv);
    base[64 + lane] = (half_t)(phi_b * inv);
}

// ---- scan helpers: quad-lookahead (WY / delta-rule identity, depth 4) ----
// Steps i=0..3 of a quad, w = state before the quad:
//   e_i = w.k_i, f_i = w.q_i                      (8 independent reduces)
//   c_i = b_i (v_i - e_i - sum_{j<i} c_j Gkk[j][i])
//   y_i = f_i + sum_{j<=i} c_j Gkq[j][i]
//   w  += sum_i c_i k_i
// Gram scalars (16/quad) are row-independent -> precomputed per chunk in LDS.
// G index map: 0:k0k1 1:k0k2 2:k0k3 3:k1k2 4:k1k3 5:k2k3
//              6:k0q0 7:k0q1 8:k0q2 9:k0q3 10:k1q1 11:k1q2 12:k1q3
//              13:k2q2 14:k2q3 15:k3q3

#define LOADK(DK, STEP)                                                     \
    {                                                                       \
        floatx4 _a = *(const floatx4*)&Ks[bufi][(STEP)][tc * 8];            \
        floatx4 _b = *(const floatx4*)&Ks[bufi][(STEP)][tc * 8 + 4];        \
        for (int _i = 0; _i < 4; ++_i) { DK[_i] = _a[_i]; DK[4 + _i] = _b[_i]; } \
    }

#define LOADQ(DQ, STEP)                                                     \
    {                                                                       \
        floatx4 _a = *(const floatx4*)&Qs[bufi][(STEP)][tc * 8];            \
        floatx4 _b = *(const floatx4*)&Qs[bufi][(STEP)][tc * 8 + 4];        \
        for (int _i = 0; _i < 4; ++_i) { DQ[_i] = _a[_i]; DQ[4 + _i] = _b[_i]; } \
    }

#define LOADG(DG, QD)                                                       \
    {                                                                       \
        *(floatx4*)&DG[0]  = *(const floatx4*)&GramLDS[(QD)][0];            \
        *(floatx4*)&DG[4]  = *(const floatx4*)&GramLDS[(QD)][4];            \
        *(floatx4*)&DG[8]  = *(const floatx4*)&GramLDS[(QD)][8];            \
        *(floatx4*)&DG[12] = *(const floatx4*)&GramLDS[(QD)][12];           \
    }

#define DOT8(RES, X, Y)                                                     \
    {                                                                       \
        float _s0 = X[0] * Y[0], _s1 = X[1] * Y[1];                         \
        _s0 = fmaf(X[2], Y[2], _s0); _s1 = fmaf(X[3], Y[3], _s1);           \
        _s0 = fmaf(X[4], Y[4], _s0); _s1 = fmaf(X[5], Y[5], _s1);           \
        _s0 = fmaf(X[6], Y[6], _s0); _s1 = fmaf(X[7], Y[7], _s1);           \
        RES = _s0 + _s1;                                                    \
    }

// One quad: 8 dots on current set, reload QQ + prefetch next K/v/b/G,
// 8 reduces, serial Gram-corrected recurrence, batched w update, 4 y stores.
#define QUAD(CK0, CK1, CK2, CK3, NK0, NK1, NK2, NK3, CG, NG, CV, CB, NV, NB, P) \
    {                                                                       \
        float _e0, _e1, _e2, _e3, _f0, _f1, _f2, _f3;                       \
        DOT8(_e0, w, CK0); DOT8(_e1, w, CK1);                               \
        DOT8(_e2, w, CK2); DOT8(_e3, w, CK3);                               \
        DOT8(_f0, w, QQ0); DOT8(_f1, w, QQ1);                               \
        DOT8(_f2, w, QQ2); DOT8(_f3, w, QQ3);                               \
        if ((P) + 1 < 8) {                                                  \
            LOADQ(QQ0, 4 * (P) + 4); LOADQ(QQ1, 4 * (P) + 5);               \
            LOADQ(QQ2, 4 * (P) + 6); LOADQ(QQ3, 4 * (P) + 7);               \
            LOADK(NK0, 4 * (P) + 4); LOADK(NK1, 4 * (P) + 5);               \
            LOADK(NK2, 4 * (P) + 6); LOADK(NK3, 4 * (P) + 7);               \
            NV[0] = Vs[bufi][4 * (P) + 4][row_l];                           \
            NV[1] = Vs[bufi][4 * (P) + 5][row_l];                           \
            NV[2] = Vs[bufi][4 * (P) + 6][row_l];                           \
            NV[3] = Vs[bufi][4 * (P) + 7][row_l];                           \
            NB[0] = Bs[bufi][4 * (P) + 4];                                  \
            NB[1] = Bs[bufi][4 * (P) + 5];                                  \
            NB[2] = Bs[bufi][4 * (P) + 6];                                  \
            NB[3] = Bs[bufi][4 * (P) + 7];                                  \
            LOADG(NG, (P) + 1);                                             \
        }                                                                   \
        _e0 = row16_allreduce(_e0); _e1 = row16_allreduce(_e1);             \
        _e2 = row16_allreduce(_e2); _e3 = row16_allreduce(_e3);             \
        _f0 = row16_allreduce(_f0); _f1 = row16_allreduce(_f1);             \
        _f2 = row16_allreduce(_f2); _f3 = row16_allreduce(_f3);             \
        float _c0 = CB[0] * (CV[0] - _e0);                                  \
        float _d1 = fmaf(_c0, CG[0], _e1);                                  \
        float _c1 = CB[1] * (CV[1] - _d1);                                  \
        float _d2 = fmaf(_c1, CG[3], fmaf(_c0, CG[1], _e2));                \
        float _c2 = CB[2] * (CV[2] - _d2);                                  \
        float _d3 = fmaf(_c2, CG[5], fmaf(_c1, CG[4], fmaf(_c0, CG[2], _e3))); \
        float _c3 = CB[3] * (CV[3] - _d3);                                  \
        float _y0 = fmaf(_c0, CG[6], _f0);                                  \
        float _y1 = fmaf(_c1, CG[10], fmaf(_c0, CG[7], _f1));               \
        float _y2 = fmaf(_c2, CG[13], fmaf(_c1, CG[11], fmaf(_c0, CG[8], _f2))); \
        float _y3 = fmaf(_c3, CG[15], fmaf(_c2, CG[14], fmaf(_c1, CG[12], fmaf(_c0, CG[9], _f3)))); \
        for (int _j = 0; _j < 8; ++_j)                                      \
            w[_j] = fmaf(_c3, CK3[_j], fmaf(_c2, CK2[_j],                   \
                    fmaf(_c1, CK1[_j], fmaf(_c0, CK0[_j], w[_j]))));        \
        if (tc == 0) {                                                      \
            ybase[(size_t)((cc * CHUNK + 4 * (P))     * BATCH + b) * 1024] = (half_t)_y0; \
            ybase[(size_t)((cc * CHUNK + 4 * (P) + 1) * BATCH + b) * 1024] = (half_t)_y1; \
            ybase[(size_t)((cc * CHUNK + 4 * (P) + 2) * BATCH + b) * 1024] = (half_t)_y2; \
            ybase[(size_t)((cc * CHUNK + 4 * (P) + 3) * BATCH + b) * 1024] = (half_t)_y3; \
        }                                                                   \
    }

// Sequential fast-weight scan, r0 geometry (proven): 256 blocks = 64 bh x 4
// row-chunks of 16 rows; 16 lanes/row, 8 fp32 state/lane; chunk staging with
// double-buffered LDS + register-held global prefetch.  Quad-lookahead inner
// loop: the dep chain (dot->reduce->coef->w) is paid once per 4 steps; the
// quad's 8 reduces are independent and pipeline.
__global__ __launch_bounds__(256, 1) void scan_kernel(const half_t* __restrict__ PhiK,
                                                      const half_t* __restrict__ PhiQ,
                                                      const float* __restrict__ V,
                                                      const float* __restrict__ Beta,
                                                      half_t* __restrict__ Y) {
    __shared__ float Ks[2][CHUNK][128];   // 32 KB
    __shared__ float Qs[2][CHUNK][128];   // 32 KB
    __shared__ float Vs[2][CHUNK][16];    //  4 KB
    __shared__ float Bs[2][CHUNK];        // 256 B
    __shared__ __align__(16) float GramLDS[8][16];  // 512 B

    const int bh = blockIdx.x >> 2;     // 0..63
    const int rc = blockIdx.x & 3;      // row chunk
    const int b = bh >> 4, h = bh & 15;
    const int tid = threadIdx.x;
    const int row_l = tid >> 4;         // 0..15
    const int tc = tid & 15;            // column group (8 floats)
    const int vrow = rc * 16 + row_l;   // 0..63

    const half_t* kg = PhiK + h * 128;
    const half_t* qg = PhiQ + h * 128;
    const float*  vg = V + h * 64 + rc * 16;
    const float*  bg = Beta + h;
    half_t* ybase = Y + h * 64 + vrow;

    // ---- stage chunk 0 directly ----
    {
        #pragma unroll
        for (int rpt = 0; rpt < 2; ++rpt) {
            int i = rpt * 256 + tid;              // 0..511
            int st = i >> 4, seg = i & 15, row = i & 15;
            size_t r = (size_t)(st * BATCH + b);
            half8 kv = *(const half8*)(kg + r * 2048 + seg * 8);
            half8 qv = *(const half8*)(qg + r * 2048 + seg * 8);
            floatx4 klo, khi, qlo, qhi;
            #pragma unroll
            for (int j = 0; j < 4; ++j) {
                klo[j] = (float)kv[j]; khi[j] = (float)kv[4 + j];
                qlo[j] = (float)qv[j]; qhi[j] = (float)qv[4 + j];
            }
            *(floatx4*)&Ks[0][st][seg * 8]     = klo;
            *(floatx4*)&Ks[0][st][seg * 8 + 4] = khi;
            *(floatx4*)&Qs[0][st][seg * 8]     = qlo;
            *(floatx4*)&Qs[0][st][seg * 8 + 4] = qhi;
            Vs[0][st][row] = vg[r * 1024 + row];
        }
        if (tid < CHUNK) {
            size_t r = (size_t)(tid * BATCH + b);
            Bs[0][tid] = bg[r * 16];
        }
    }
    __syncthreads();

    float w[8];
    #pragma unroll
    for (int j = 0; j < 8; ++j) w[j] = 0.f;

    for (int cc = 0; cc < NCHUNK; ++cc) {
        const int bufi = cc & 1;
        const bool more = (cc + 1 < NCHUNK);

        // ---- issue global loads for chunk cc+1 (fly during Gram + quads) ----
        half8 pk[2], pq[2];
        float pv[2], pb = 0.f;
        if (more) {
            #pragma unroll
            for (int rpt = 0; rpt < 2; ++rpt) {
                int i = rpt * 256 + tid;
                int st = i >> 4, seg = i & 15, row = i & 15;
                size_t r = (size_t)(((cc + 1) * CHUNK + st) * BATCH + b);
                pk[rpt] = *(const half8*)(kg + r * 2048 + seg * 8);
                pq[rpt] = *(const half8*)(qg + r * 2048 + seg * 8);
                pv[rpt] = vg[r * 1024 + row];
            }
            if (tid < CHUNK) {
                size_t r = (size_t)(((cc + 1) * CHUNK + tid) * BATCH + b);
                pb = bg[r * 16];
            }
        }

        // ---- Gram precompute: lane-group g handles quad (g&7); groups 8-15
        // duplicate (uniform code, no divergence) ----
        {
            const int qd = row_l & 7;
            float k0[8], k1[8], k2[8], k3[8], q0[8], q1[8], q2[8], q3[8];
            LOADK(k0, 4 * qd);     LOADK(k1, 4 * qd + 1);
            LOADK(k2, 4 * qd + 2); LOADK(k3, 4 * qd + 3);
            LOADQ(q0, 4 * qd);     LOADQ(q1, 4 * qd + 1);
            LOADQ(q2, 4 * qd + 2); LOADQ(q3, 4 * qd + 3);
            float g[16];
            DOT8(g[0],  k0, k1); DOT8(g[1],  k0, k2); DOT8(g[2],  k0, k3);
            DOT8(g[3],  k1, k2); DOT8(g[4],  k1, k3); DOT8(g[5],  k2, k3);
            DOT8(g[6],  k0, q0); DOT8(g[7],  k0, q1); DOT8(g[8],  k0, q2);
            DOT8(g[9],  k0, q3); DOT8(g[10], k1, q1); DOT8(g[11], k1, q2);
            DOT8(g[12], k1, q3); DOT8(g[13], k2, q2); DOT8(g[14], k2, q3);
            DOT8(g[15], k3, q3);
            #pragma unroll
            for (int i = 0; i < 16; ++i) g[i] = row16_allreduce(g[i]);
            if (tc == 0 && row_l < 8) {
                #pragma unroll
                for (int i = 0; i < 16; ++i) GramLDS[qd][i] = g[i];
            }
        }
        __syncthreads();   // Gram visible

        // ---- preload quad 0 into set A ----
        float KA0[8], KA1[8], KA2[8], KA3[8];
        float KB0[8], KB1[8], KB2[8], KB3[8];
        float QQ0[8], QQ1[8], QQ2[8], QQ3[8];
        float GA[16], GB[16];
        float vA[4], vB[4], bA[4], bB[4];
        LOADK(KA0, 0); LOADK(KA1, 1); LOADK(KA2, 2); LOADK(KA3, 3);
        LOADQ(QQ0, 0); LOADQ(QQ1, 1); LOADQ(QQ2, 2); LOADQ(QQ3, 3);
        vA[0] = Vs[bufi][0][row_l]; vA[1] = Vs[bufi][1][row_l];
        vA[2] = Vs[bufi][2][row_l]; vA[3] = Vs[bufi][3][row_l];
        bA[0] = Bs[bufi][0]; bA[1] = Bs[bufi][1];
        bA[2] = Bs[bufi][2]; bA[3] = Bs[bufi][3];
        LOADG(GA, 0);

        // ---- 8 quads, ping-pong K/G/v/b sets; QQ reloaded in place ----
        #pragma unroll 1
        for (int p = 0; p < 8; p += 2) {
            QUAD(KA0, KA1, KA2, KA3, KB0, KB1, KB2, KB3, GA, GB, vA, bA, vB, bB, p);
            QUAD(KB0, KB1, KB2, KB3, KA0, KA1, KA2, KA3, GB, GA, vB, bB, vA, bA, p + 1);
        }

        // ---- write staged chunk cc+1 into the other buffer ----
        if (more) {
            const int bufn = bufi ^ 1;
            #pragma unroll
            for (int rpt = 0; rpt < 2; ++rpt) {
                int i = rpt * 256 + tid;
                int st = i >> 4, seg = i & 15, row = i & 15;
                floatx4 klo, khi, qlo, qhi;
                #pragma unroll
                for (int j = 0; j < 4; ++j) {
                    klo[j] = (float)pk[rpt][j]; khi[j] = (float)pk[rpt][4 + j];
                    qlo[j] = (float)pq[rpt][j]; qhi[j] = (float)pq[rpt][4 + j];
                }
                *(floatx4*)&Ks[bufn][st][seg * 8]     = klo;
                *(floatx4*)&Ks[bufn][st][seg * 8 + 4] = khi;
                *(floatx4*)&Qs[bufn][st][seg * 8]     = qlo;
                *(floatx4*)&Qs[bufn][st][seg * 8 + 4] = qhi;
                Vs[bufn][st][row] = pv[rpt];
            }
            if (tid < CHUNK) Bs[bufn][tid] = pb;
        }
        __syncthreads();
    }
}

extern "C" void kernel_launch(void* const* d_in, const int* in_sizes, int n_in,
                              void* d_out, int out_size, void* d_ws, size_t ws_size,
                              hipStream_t stream) {
    const float* x  = (const float*)d_in[0];
    const float* Wq = (const float*)d_in[1];
    const float* Wk = (const float*)d_in[2];
    const float* Wv = (const float*)d_in[3];
    const float* Wb = (const float*)d_in[4];
    const float* Wo = (const float*)d_in[5];
    const float* bo = (const float*)d_in[6];

    char* ws = (char*)d_ws;
    size_t off = 0;
    auto alloc = [&](size_t bytes) -> void* {
        void* p = ws + off;
        off += (bytes + 255) & ~(size_t)255;
        return p;
    };
    half_t* PhiQ = (half_t*)alloc((size_t)NROWS * 2048 * 2);  // 64 MB
    half_t* PhiK = (half_t*)alloc((size_t)NROWS * 2048 * 2);  // 64 MB
    half_t* Yb   = (half_t*)alloc((size_t)NROWS * 1024 * 2);  // 32 MB
    float*  Beta = (float*)alloc((size_t)NROWS * 16 * 4);     //  1 MB
    float*  Wqt  = (float*)alloc((size_t)1024 * 1024 * 4);    //  4 MB
    float*  Wkt  = (float*)alloc((size_t)1024 * 1024 * 4);
    float*  Wvt  = (float*)alloc((size_t)1024 * 1024 * 4);
    float*  Wot  = (float*)alloc((size_t)1024 * 1024 * 4);
    float*  Wbt  = (float*)alloc((size_t)16 * 1024 * 4);
    float*  Vb   = (float*)d_out;  // V staged in d_out (fp32, dead before final GEMM)

    transpose_k<<<4096, 256, 0, stream>>>(Wq, Wqt, 1024, 1024);
    transpose_k<<<4096, 256, 0, stream>>>(Wk, Wkt, 1024, 1024);
    transpose_k<<<4096, 256, 0, stream>>>(Wv, Wvt, 1024, 1024);
    transpose_k<<<4096, 256, 0, stream>>>(Wo, Wot, 1024, 1024);
    transpose_k<<<64,   256, 0, stream>>>(Wb, Wbt, 1024, 16);

    dim3 ggrid(NROWS / 64, DIM / 64);
    const int dgrid = (NROWS * 16) / 4;
    gemm_bt<float, 1><<<ggrid, 256, 0, stream>>>(x, Wqt, PhiQ, nullptr, DIM, DIM);
    dpfp_h<<<dgrid, 256, 0, stream>>>(PhiQ);
    gemm_bt<float, 1><<<ggrid, 256, 0, stream>>>(x, Wkt, PhiK, nullptr, DIM, DIM);
    dpfp_h<<<dgrid, 256, 0, stream>>>(PhiK);
    gemm_bt<float, 0><<<ggrid, 256, 0, stream>>>(x, Wvt, Vb, nullptr, DIM, DIM);
    beta_kernel<<<NROWS / 4, 256, 0, stream>>>(x, Wbt, Beta);
    scan_kernel<<<256, 256, 0, stream>>>(PhiK, PhiQ, Vb, Beta, Yb);
    gemm_bt<half_t, 0><<<ggrid, 256, 0, stream>>>(Yb, Wot, d_out, bo, DIM, DIM);
}

// Round 8
// 1453.575 us; speedup vs baseline: 1.1722x; 1.1722x over previous
//
#include <hip/hip_runtime.h>

#define S_LEN 4096
#define BATCH 4
#define NROWS 16384   // S*B
#define DIM   1024
#define CHUNK 32
#define NCHUNK (S_LEN / CHUNK)

typedef __attribute__((ext_vector_type(8))) short short8;
typedef __attribute__((ext_vector_type(4))) float floatx4;
typedef _Float16 half_t;
typedef __attribute__((ext_vector_type(8))) _Float16 half8;

__device__ __forceinline__ float bf2f(short s) {
    union { unsigned int u; float f; } c;
    c.u = ((unsigned int)(unsigned short)s) << 16;
    return c.f;
}
__device__ __forceinline__ short f2bf(float f) {
    union { float f; unsigned int u; } c; c.f = f;
    unsigned int r = c.u + 0x7fffu + ((c.u >> 16) & 1u);
    return (short)(r >> 16);
}
// split fp32 -> bf16 hi + bf16 lo (a ~= hi + lo, rel err ~2^-16)
__device__ __forceinline__ void split_bf16(float x, short& hi, short& lo) {
    short h = f2bf(x);
    hi = h;
    lo = f2bf(x - bf2f(h));
}

// 16-lane (DPP row) all-reduce sum: quad_perm xor1, xor2, row_ror:4, row_ror:8.
__device__ __forceinline__ float row16_allreduce(float x) {
    union fi { float f; int i; };
    fi a, b;
    a.f = x;
    b.i = __builtin_amdgcn_update_dpp(0, a.i, 0xB1,  0xF, 0xF, true); a.f += b.f; // xor1
    b.i = __builtin_amdgcn_update_dpp(0, a.i, 0x4E,  0xF, 0xF, true); a.f += b.f; // xor2
    b.i = __builtin_amdgcn_update_dpp(0, a.i, 0x124, 0xF, 0xF, true); a.f += b.f; // ror4
    b.i = __builtin_amdgcn_update_dpp(0, a.i, 0x128, 0xF, 0xF, true); a.f += b.f; // ror8
    return a.f;
}

// W[K][N] fp32 row-major -> Wt[N][K]
__global__ __launch_bounds__(256) void transpose_k(const float* __restrict__ W,
                                                   float* __restrict__ Wt,
                                                   int K, int N) {
    int idx = blockIdx.x * 256 + threadIdx.x;
    if (idx >= N * K) return;
    int n = idx / K;
    int k = idx - n * K;
    Wt[idx] = W[k * N + n];
}

// C = A[M,K] @ Bt[N,K]^T. A fp32 or fp16, Bt fp32. Split-bf16 3-term MFMA, fp32 acc.
// 128x128 tile, 4 waves (2x2), 4x4 16x16 frags per wave: MFMA:ds_read = 48:16
// per K-step (vs 12:10 at 64^2) and staging amortized 4x per output.
// MODE 0: fp32 out at row*N+col (+ optional fp32 bias)
// MODE 1: fp16 out at row*2048 + (col>>6)*128 + (col&63)   (dpfp staging layout)
template <typename AT, int MODE>
__global__ __launch_bounds__(256) void gemm_bt(const AT* __restrict__ A,
                                               const float* __restrict__ Bt,
                                               void* __restrict__ Cout,
                                               const float* __restrict__ bias,
                                               int N, int K) {
    __shared__ __align__(16) short As_h[128][40], As_l[128][40];   // 20 KB
    __shared__ __align__(16) short Bs_h[128][40], Bs_l[128][40];   // 20 KB
    const int tid  = threadIdx.x;
    const int wave = tid >> 6, lane = tid & 63;
    const int wr = wave >> 1, wc = wave & 1;       // 2x2 wave grid
    const int row0 = blockIdx.x * 128, col0 = blockIdx.y * 128;
    const int lr = tid >> 1, lc = (tid & 1) * 16;  // staging: 128 rows x 2 groups of 16
    const AT*    Ap = A  + (size_t)(row0 + lr) * K + lc;
    const float* Bp = Bt + (size_t)(col0 + lr) * K + lc;
    const int fr = lane & 15;                      // frag row within 16
    const int ak = (lane >> 4) * 8;                // k-slice start
    floatx4 acc[4][4];
    #pragma unroll
    for (int m = 0; m < 4; ++m)
        #pragma unroll
        for (int n = 0; n < 4; ++n) acc[m][n] = (floatx4){0.f, 0.f, 0.f, 0.f};

    for (int k0 = 0; k0 < K; k0 += 32) {
        float av[16], bv[16];
        if constexpr (sizeof(AT) == 4) {
            #pragma unroll
            for (int g = 0; g < 4; ++g) {
                floatx4 a = *(const floatx4*)(Ap + k0 + g * 4);
                #pragma unroll
                for (int j = 0; j < 4; ++j) av[g * 4 + j] = a[j];
            }
        } else {
            #pragma unroll
            for (int g = 0; g < 2; ++g) {
                half8 a = *(const half8*)(Ap + k0 + g * 8);
                #pragma unroll
                for (int j = 0; j < 8; ++j) av[g * 8 + j] = (float)a[j];
            }
        }
        #pragma unroll
        for (int g = 0; g < 4; ++g) {
            floatx4 v = *(const floatx4*)(Bp + k0 + g * 4);
            #pragma unroll
            for (int j = 0; j < 4; ++j) bv[g * 4 + j] = v[j];
        }

        short8 ah[2], al[2], bh[2], bl[2];
        #pragma unroll
        for (int g = 0; g < 2; ++g)
            #pragma unroll
            for (int j = 0; j < 8; ++j) {
                short h, l;
                split_bf16(av[g * 8 + j], h, l); ah[g][j] = h; al[g][j] = l;
                split_bf16(bv[g * 8 + j], h, l); bh[g][j] = h; bl[g][j] = l;
            }
        #pragma unroll
        for (int g = 0; g < 2; ++g) {
            *(short8*)&As_h[lr][lc + g * 8] = ah[g];
            *(short8*)&As_l[lr][lc + g * 8] = al[g];
            *(short8*)&Bs_h[lr][lc + g * 8] = bh[g];
            *(short8*)&Bs_l[lr][lc + g * 8] = bl[g];
        }
        __syncthreads();

        short8 afh[4], afl[4], bfh[4], bfl[4];
        #pragma unroll
        for (int m = 0; m < 4; ++m) {
            afh[m] = *(const short8*)&As_h[wr * 64 + m * 16 + fr][ak];
            afl[m] = *(const short8*)&As_l[wr * 64 + m * 16 + fr][ak];
        }
        #pragma unroll
        for (int n = 0; n < 4; ++n) {
            bfh[n] = *(const short8*)&Bs_h[wc * 64 + n * 16 + fr][ak];
            bfl[n] = *(const short8*)&Bs_l[wc * 64 + n * 16 + fr][ak];
        }
        #pragma unroll
        for (int m = 0; m < 4; ++m)
            #pragma unroll
            for (int n = 0; n < 4; ++n) {
                acc[m][n] = __builtin_amdgcn_mfma_f32_16x16x32_bf16(afh[m], bfh[n], acc[m][n], 0, 0, 0);
                acc[m][n] = __builtin_amdgcn_mfma_f32_16x16x32_bf16(afh[m], bfl[n], acc[m][n], 0, 0, 0);
                acc[m][n] = __builtin_amdgcn_mfma_f32_16x16x32_bf16(afl[m], bfh[n], acc[m][n], 0, 0, 0);
            }
        __syncthreads();
    }
    // C/D layout (verified m89/m91): col = lane&15, row = (lane>>4)*4 + reg
    #pragma unroll
    for (int m = 0; m < 4; ++m) {
        const int crow = row0 + wr * 64 + m * 16 + (lane >> 4) * 4;
        #pragma unroll
        for (int n = 0; n < 4; ++n) {
            const int col = col0 + wc * 64 + n * 16 + (lane & 15);
            #pragma unroll
            for (int r = 0; r < 4; ++r) {
                int row = crow + r;
                float v = acc[m][n][r];
                if (MODE == 0) {
                    float bb = bias ? bias[col] : 0.f;
                    ((float*)Cout)[(size_t)row * N + col] = v + bb;
                } else {
                    ((half_t*)Cout)[(size_t)row * 2048 + (col >> 6) * 128 + (col & 63)] = (half_t)v;
                }
            }
        }
    }
}

// beta = sigmoid(x @ Wb); one wave per row, Wbt fp32 [16][1024]
__global__ __launch_bounds__(256) void beta_kernel(const float* __restrict__ X,
                                                   const float* __restrict__ Wbt,
                                                   float* __restrict__ Beta) {
    int wid  = (blockIdx.x * 256 + threadIdx.x) >> 6;
    int lane = threadIdx.x & 63;
    if (wid >= NROWS) return;
    const float* xr = X + (size_t)wid * DIM + lane * 16;
    float xv[16];
    #pragma unroll
    for (int j = 0; j < 4; ++j) {
        floatx4 v = *(const floatx4*)(xr + j * 4);
        #pragma unroll
        for (int e = 0; e < 4; ++e) xv[j * 4 + e] = v[e];
    }
    #pragma unroll 1
    for (int h = 0; h < 16; ++h) {
        const float* wr = Wbt + h * DIM + lane * 16;
        float s = 0.f;
        #pragma unroll
        for (int j = 0; j < 4; ++j) {
            floatx4 v = *(const floatx4*)(wr + j * 4);
            #pragma unroll
            for (int e = 0; e < 4; ++e) s = fmaf(xv[j * 4 + e], v[e], s);
        }
        #pragma unroll
        for (int off = 32; off; off >>= 1) s += __shfl_xor(s, off);
        if (lane == 0) Beta[wid * 16 + h] = 1.f / (1.f + __expf(-s));
    }
}

// In-place DPFP on fp16 spans of 128 (first 64 hold raw p, written by gemm MODE 1).
__global__ __launch_bounds__(256) void dpfp_h(half_t* __restrict__ P) {
    int gw   = (blockIdx.x * 256 + threadIdx.x) >> 6;
    int lane = threadIdx.x & 63;
    half_t* base = P + (size_t)gw * 128;
    float p  = (float)base[lane];
    float pm = __shfl(p, (lane + 63) & 63);           // p[lane-1], lane0 gets p[63]
    float rp  = fmaxf(p, 0.f),  rn  = fmaxf(-p, 0.f);
    float rpm = fmaxf(pm, 0.f), rnm = fmaxf(-pm, 0.f);
    float aprev = (lane == 0) ? rnm : rpm;            // xc[(lane-1)%128]
    float bprev = (lane == 0) ? rpm : rnm;            // xc[lane+63]
    float phi_a = rp * aprev;                         // phi[lane]
    float phi_b = rn * bprev;                         // phi[lane+64]
    float s = phi_a + phi_b;
    #pragma unroll
    for (int off = 32; off; off >>= 1) s += __shfl_xor(s, off);
    float inv = 1.f / (s + 1e-6f);
    base[lane]      = (half_t)(phi_a * inv);
    base[64 + lane] = (half_t)(phi_b * inv);
}

// ---- scan helpers: pair-lookahead (WY / delta-rule identity) ----
// Per pair of steps (even step E, odd step O), with w = state before the pair:
//   e0 = w.kE, e1 = w.kO, f0 = w.qE, f1 = w.qO   (4 independent reduces)
//   c0 = bE (vE - e0)
//   d1 = e1 + c0 * (kE.kO)            <- Gram scalar
//   c1 = bO (vO - d1)
//   y0 = f0 + c0 * (kE.qE)
//   y1 = f1 + c0 * (kE.qO) + c1 * (kO.qO)
//   w += c0 kE + c1 kO
// Gram scalars are row-independent -> precomputed once per chunk in LDS.
// (r7 lesson: depth-4 lookahead blows the register budget (136 VGPR) and the
// scheduler serializes the reduce chains — depth 2 is the local optimum.)

#define LOADSTEP(DK, DQ, STEP)                                              \
    {                                                                       \
        floatx4 _ka = *(const floatx4*)&Ks[bufi][STEP][tc * 8];             \
        floatx4 _kb = *(const floatx4*)&Ks[bufi][STEP][tc * 8 + 4];         \
        floatx4 _qa = *(const floatx4*)&Qs[bufi][STEP][tc * 8];             \
        floatx4 _qb = *(const floatx4*)&Qs[bufi][STEP][tc * 8 + 4];         \
        for (int _i = 0; _i < 4; ++_i) {                                    \
            DK[_i] = _ka[_i]; DK[4 + _i] = _kb[_i];                         \
            DQ[_i] = _qa[_i]; DQ[4 + _i] = _qb[_i];                         \
        }                                                                   \
    }

#define DOT8(RES, X, Y)                                                     \
    {                                                                       \
        float _s0 = X[0] * Y[0], _s1 = X[1] * Y[1];                         \
        _s0 = fmaf(X[2], Y[2], _s0); _s1 = fmaf(X[3], Y[3], _s1);           \
        _s0 = fmaf(X[4], Y[4], _s0); _s1 = fmaf(X[5], Y[5], _s1);           \
        _s0 = fmaf(X[6], Y[6], _s0); _s1 = fmaf(X[7], Y[7], _s1);           \
        RES = _s0 + _s1;                                                    \
    }

// One pair: prefetch pair P+1 into the N* register set, 4 dots+reduces on C*,
// tiny serial part, batched w update, y stores.
#define PAIR(CEK, CEQ, COK, COQ, CEV, CEB, COV, COB, CG,                    \
             NEK, NEQ, NOK, NOQ, NEV, NEB, NOV, NOB, NG, P)                 \
    {                                                                       \
        if ((P) + 1 < 16) {                                                 \
            LOADSTEP(NEK, NEQ, 2 * (P) + 2);                                \
            LOADSTEP(NOK, NOQ, 2 * (P) + 3);                                \
            NEV = Vs[bufi][2 * (P) + 2][row_l];                             \
            NEB = Bs[bufi][2 * (P) + 2];                                    \
            NOV = Vs[bufi][2 * (P) + 3][row_l];                             \
            NOB = Bs[bufi][2 * (P) + 3];                                    \
            NG  = *(const floatx4*)&GramLDS[(P) + 1][0];                    \
        }                                                                   \
        float _e0, _e1, _f0, _f1;                                           \
        DOT8(_e0, w, CEK); DOT8(_e1, w, COK);                               \
        DOT8(_f0, w, CEQ); DOT8(_f1, w, COQ);                               \
        _e0 = row16_allreduce(_e0); _e1 = row16_allreduce(_e1);             \
        _f0 = row16_allreduce(_f0); _f1 = row16_allreduce(_f1);             \
        float _c0 = CEB * (CEV - _e0);                                      \
        float _d1 = fmaf(_c0, CG[0], _e1);                                  \
        float _c1 = COB * (COV - _d1);                                      \
        float _y0 = fmaf(_c0, CG[1], _f0);                                  \
        float _y1 = fmaf(_c1, CG[3], fmaf(_c0, CG[2], _f1));                \
        for (int _j = 0; _j < 8; ++_j)                                      \
            w[_j] = fmaf(_c1, COK[_j], fmaf(_c0, CEK[_j], w[_j]));          \
        if (tc == 0) {                                                      \
            ybase[(size_t)((cc * CHUNK + 2 * (P))     * BATCH + b) * 1024] = (half_t)_y0; \
            ybase[(size_t)((cc * CHUNK + 2 * (P) + 1) * BATCH + b) * 1024] = (half_t)_y1; \
        }                                                                   \
    }

// Sequential fast-weight scan, r0 geometry (proven): 256 blocks = 64 bh x 4
// row-chunks of 16 rows; 16 lanes/row, 8 fp32 state/lane; chunk staging with
// double-buffered LDS + register-held global prefetch.  Pair-lookahead inner
// loop (measured 660 us): the ~470-cyc dep chain is paid once per 2 steps and
// the pair's 4 reduces pipeline.
__global__ __launch_bounds__(256, 1) void scan_kernel(const half_t* __restrict__ PhiK,
                                                      const half_t* __restrict__ PhiQ,
                                                      const float* __restrict__ V,
                                                      const float* __restrict__ Beta,
                                                      half_t* __restrict__ Y) {
    __shared__ float Ks[2][CHUNK][128];   // 32 KB
    __shared__ float Qs[2][CHUNK][128];   // 32 KB
    __shared__ float Vs[2][CHUNK][16];    //  4 KB
    __shared__ float Bs[2][CHUNK];        // 256 B
    __shared__ float GramLDS[16][4];      // 256 B: per pair {kE.kO, kE.qE, kE.qO, kO.qO}

    const int bh = blockIdx.x >> 2;     // 0..63
    const int rc = blockIdx.x & 3;      // row chunk
    const int b = bh >> 4, h = bh & 15;
    const int tid = threadIdx.x;
    const int row_l = tid >> 4;         // 0..15
    const int tc = tid & 15;            // column group (8 floats)
    const int vrow = rc * 16 + row_l;   // 0..63

    const half_t* kg = PhiK + h * 128;
    const half_t* qg = PhiQ + h * 128;
    const float*  vg = V + h * 64 + rc * 16;
    const float*  bg = Beta + h;
    half_t* ybase = Y + h * 64 + vrow;

    // ---- stage chunk 0 directly ----
    {
        #pragma unroll
        for (int rpt = 0; rpt < 2; ++rpt) {
            int i = rpt * 256 + tid;              // 0..511
            int st = i >> 4, seg = i & 15, row = i & 15;
            size_t r = (size_t)(st * BATCH + b);
            half8 kv = *(const half8*)(kg + r * 2048 + seg * 8);
            half8 qv = *(const half8*)(qg + r * 2048 + seg * 8);
            floatx4 klo, khi, qlo, qhi;
            #pragma unroll
            for (int j = 0; j < 4; ++j) {
                klo[j] = (float)kv[j]; khi[j] = (float)kv[4 + j];
                qlo[j] = (float)qv[j]; qhi[j] = (float)qv[4 + j];
            }
            *(floatx4*)&Ks[0][st][seg * 8]     = klo;
            *(floatx4*)&Ks[0][st][seg * 8 + 4] = khi;
            *(floatx4*)&Qs[0][st][seg * 8]     = qlo;
            *(floatx4*)&Qs[0][st][seg * 8 + 4] = qhi;
            Vs[0][st][row] = vg[r * 1024 + row];
        }
        if (tid < CHUNK) {
            size_t r = (size_t)(tid * BATCH + b);
            Bs[0][tid] = bg[r * 16];
        }
    }
    __syncthreads();

    float w[8];
    #pragma unroll
    for (int j = 0; j < 8; ++j) w[j] = 0.f;

    for (int cc = 0; cc < NCHUNK; ++cc) {
        const int bufi = cc & 1;
        const bool more = (cc + 1 < NCHUNK);

        // ---- Gram precompute for chunk cc: row-group g handles pair g ----
        {
            float ka[8], kb[8], qa[8], qb[8];
            LOADSTEP(ka, qa, 2 * row_l);
            LOADSTEP(kb, qb, 2 * row_l + 1);
            float skk, s00, s01, s11;
            DOT8(skk, ka, kb);
            DOT8(s00, ka, qa);
            DOT8(s01, ka, qb);
            DOT8(s11, kb, qb);
            skk = row16_allreduce(skk);
            s00 = row16_allreduce(s00);
            s01 = row16_allreduce(s01);
            s11 = row16_allreduce(s11);
            if (tc == 0) {
                GramLDS[row_l][0] = skk;
                GramLDS[row_l][1] = s00;
                GramLDS[row_l][2] = s01;
                GramLDS[row_l][3] = s11;
            }
        }
        __syncthreads();   // Gram visible (LDS-only traffic -> cheap drain)

        // ---- issue global loads for chunk cc+1 (held in regs until after compute) ----
        half8 pk[2], pq[2];
        float pv[2], pb = 0.f;
        if (more) {
            #pragma unroll
            for (int rpt = 0; rpt < 2; ++rpt) {
                int i = rpt * 256 + tid;
                int st = i >> 4, seg = i & 15, row = i & 15;
                size_t r = (size_t)(((cc + 1) * CHUNK + st) * BATCH + b);
                pk[rpt] = *(const half8*)(kg + r * 2048 + seg * 8);
                pq[rpt] = *(const half8*)(qg + r * 2048 + seg * 8);
                pv[rpt] = vg[r * 1024 + row];
            }
            if (tid < CHUNK) {
                size_t r = (size_t)(((cc + 1) * CHUNK + tid) * BATCH + b);
                pb = bg[r * 16];
            }
        }

        // ---- preload pair 0 (set 0) ----
        float EK0[8], EQ0[8], OK0[8], OQ0[8];
        float EK1[8], EQ1[8], OK1[8], OQ1[8];
        float Ev0, Eb0, Ov0, Ob0, Ev1, Eb1, Ov1, Ob1;
        floatx4 G0, G1;
        LOADSTEP(EK0, EQ0, 0);
        LOADSTEP(OK0, OQ0, 1);
        Ev0 = Vs[bufi][0][row_l]; Eb0 = Bs[bufi][0];
        Ov0 = Vs[bufi][1][row_l]; Ob0 = Bs[bufi][1];
        G0 = *(const floatx4*)&GramLDS[0][0];

        // ---- 16 pairs, ping-pong register sets ----
        #pragma unroll 1
        for (int p2 = 0; p2 < 16; p2 += 2) {
            PAIR(EK0, EQ0, OK0, OQ0, Ev0, Eb0, Ov0, Ob0, G0,
                 EK1, EQ1, OK1, OQ1, Ev1, Eb1, Ov1, Ob1, G1, p2);
            PAIR(EK1, EQ1, OK1, OQ1, Ev1, Eb1, Ov1, Ob1, G1,
                 EK0, EQ0, OK0, OQ0, Ev0, Eb0, Ov0, Ob0, G0, p2 + 1);
        }

        // ---- write staged chunk cc+1 into the other buffer ----
        if (more) {
            const int bufn = bufi ^ 1;
            #pragma unroll
            for (int rpt = 0; rpt < 2; ++rpt) {
                int i = rpt * 256 + tid;
                int st = i >> 4, seg = i & 15, row = i & 15;
                floatx4 klo, khi, qlo, qhi;
                #pragma unroll
                for (int j = 0; j < 4; ++j) {
                    klo[j] = (float)pk[rpt][j]; khi[j] = (float)pk[rpt][4 + j];
                    qlo[j] = (float)pq[rpt][j]; qhi[j] = (float)pq[rpt][4 + j];
                }
                *(floatx4*)&Ks[bufn][st][seg * 8]     = klo;
                *(floatx4*)&Ks[bufn][st][seg * 8 + 4] = khi;
                *(floatx4*)&Qs[bufn][st][seg * 8]     = qlo;
                *(floatx4*)&Qs[bufn][st][seg * 8 + 4] = qhi;
                Vs[bufn][st][row] = pv[rpt];
            }
            if (tid < CHUNK) Bs[bufn][tid] = pb;
        }
        __syncthreads();
    }
}

extern "C" void kernel_launch(void* const* d_in, const int* in_sizes, int n_in,
                              void* d_out, int out_size, void* d_ws, size_t ws_size,
                              hipStream_t stream) {
    const float* x  = (const float*)d_in[0];
    const float* Wq = (const float*)d_in[1];
    const float* Wk = (const float*)d_in[2];
    const float* Wv = (const float*)d_in[3];
    const float* Wb = (const float*)d_in[4];
    const float* Wo = (const float*)d_in[5];
    const float* bo = (const float*)d_in[6];

    char* ws = (char*)d_ws;
    size_t off = 0;
    auto alloc = [&](size_t bytes) -> void* {
        void* p = ws + off;
        off += (bytes + 255) & ~(size_t)255;
        return p;
    };
    half_t* PhiQ = (half_t*)alloc((size_t)NROWS * 2048 * 2);  // 64 MB
    half_t* PhiK = (half_t*)alloc((size_t)NROWS * 2048 * 2);  // 64 MB
    half_t* Yb   = (half_t*)alloc((size_t)NROWS * 1024 * 2);  // 32 MB
    float*  Beta = (float*)alloc((size_t)NROWS * 16 * 4);     //  1 MB
    float*  Wqt  = (float*)alloc((size_t)1024 * 1024 * 4);    //  4 MB
    float*  Wkt  = (float*)alloc((size_t)1024 * 1024 * 4);
    float*  Wvt  = (float*)alloc((size_t)1024 * 1024 * 4);
    float*  Wot  = (float*)alloc((size_t)1024 * 1024 * 4);
    float*  Wbt  = (float*)alloc((size_t)16 * 1024 * 4);
    float*  Vb   = (float*)d_out;  // V staged in d_out (fp32, dead before final GEMM)

    transpose_k<<<4096, 256, 0, stream>>>(Wq, Wqt, 1024, 1024);
    transpose_k<<<4096, 256, 0, stream>>>(Wk, Wkt, 1024, 1024);
    transpose_k<<<4096, 256, 0, stream>>>(Wv, Wvt, 1024, 1024);
    transpose_k<<<4096, 256, 0, stream>>>(Wo, Wot, 1024, 1024);
    transpose_k<<<64,   256, 0, stream>>>(Wb, Wbt, 1024, 16);

    dim3 ggrid(NROWS / 128, DIM / 128);
    const int dgrid = (NROWS * 16) / 4;
    gemm_bt<float, 1><<<ggrid, 256, 0, stream>>>(x, Wqt, PhiQ, nullptr, DIM, DIM);
    dpfp_h<<<dgrid, 256, 0, stream>>>(PhiQ);
    gemm_bt<float, 1><<<ggrid, 256, 0, stream>>>(x, Wkt, PhiK, nullptr, DIM, DIM);
    dpfp_h<<<dgrid, 256, 0, stream>>>(PhiK);
    gemm_bt<float, 0><<<ggrid, 256, 0, stream>>>(x, Wvt, Vb, nullptr, DIM, DIM);
    beta_kernel<<<NROWS / 4, 256, 0, stream>>>(x, Wbt, Beta);
    scan_kernel<<<256, 256, 0, stream>>>(PhiK, PhiQ, Vb, Beta, Yb);
    gemm_bt<half_t, 0><<<ggrid, 256, 0, stream>>>(Yb, Wot, d_out, bo, DIM, DIM);
}

// Round 9
// 1438.078 us; speedup vs baseline: 1.1849x; 1.0108x over previous
//
#include <hip/hip_runtime.h>

#define S_LEN 4096
#define BATCH 4
#define NROWS 16384   // S*B
#define DIM   1024
#define CHUNK 32
#define NCHUNK (S_LEN / CHUNK)

typedef __attribute__((ext_vector_type(8))) short short8;
typedef __attribute__((ext_vector_type(4))) float floatx4;
typedef _Float16 half_t;
typedef __attribute__((ext_vector_type(8))) _Float16 half8;

__device__ __forceinline__ float bf2f(short s) {
    union { unsigned int u; float f; } c;
    c.u = ((unsigned int)(unsigned short)s) << 16;
    return c.f;
}
__device__ __forceinline__ short f2bf(float f) {
    union { float f; unsigned int u; } c; c.f = f;
    unsigned int r = c.u + 0x7fffu + ((c.u >> 16) & 1u);
    return (short)(r >> 16);
}
// split fp32 -> bf16 hi + bf16 lo (a ~= hi + lo, rel err ~2^-16)
__device__ __forceinline__ void split_bf16(float x, short& hi, short& lo) {
    short h = f2bf(x);
    hi = h;
    lo = f2bf(x - bf2f(h));
}

// 16-lane (DPP row) all-reduce sum: quad_perm xor1, xor2, row_ror:4, row_ror:8.
__device__ __forceinline__ float row16_allreduce(float x) {
    union fi { float f; int i; };
    fi a, b;
    a.f = x;
    b.i = __builtin_amdgcn_update_dpp(0, a.i, 0xB1,  0xF, 0xF, true); a.f += b.f; // xor1
    b.i = __builtin_amdgcn_update_dpp(0, a.i, 0x4E,  0xF, 0xF, true); a.f += b.f; // xor2
    b.i = __builtin_amdgcn_update_dpp(0, a.i, 0x124, 0xF, 0xF, true); a.f += b.f; // ror4
    b.i = __builtin_amdgcn_update_dpp(0, a.i, 0x128, 0xF, 0xF, true); a.f += b.f; // ror8
    return a.f;
}

// W[K][N] fp32 row-major -> Wt[N][K]  (small fp32 transpose, used for Wb)
__global__ __launch_bounds__(256) void transpose_k(const float* __restrict__ W,
                                                   float* __restrict__ Wt,
                                                   int K, int N) {
    int idx = blockIdx.x * 256 + threadIdx.x;
    if (idx >= N * K) return;
    int n = idx / K;
    int k = idx - n * K;
    Wt[idx] = W[k * N + n];
}

// W[K][N] fp32 -> transposed split-bf16 planes Wth/Wtl [N][K]
__global__ __launch_bounds__(256) void transpose_split(const float* __restrict__ W,
                                                       short* __restrict__ Wth,
                                                       short* __restrict__ Wtl,
                                                       int K, int N) {
    int idx = blockIdx.x * 256 + threadIdx.x;
    if (idx >= N * K) return;
    int n = idx / K;
    int k = idx - n * K;
    short h, l;
    split_bf16(W[k * N + n], h, l);
    Wth[idx] = h;
    Wtl[idx] = l;
}

// fp32 stream -> split-bf16 planes (8 elems/thread, coalesced)
__global__ __launch_bounds__(256) void split_f32(const float* __restrict__ X,
                                                 short* __restrict__ Xh,
                                                 short* __restrict__ Xl) {
    size_t idx = ((size_t)blockIdx.x * 256 + threadIdx.x) * 8;
    floatx4 a = *(const floatx4*)(X + idx);
    floatx4 b = *(const floatx4*)(X + idx + 4);
    short8 h, l;
    #pragma unroll
    for (int j = 0; j < 4; ++j) {
        short hh, ll;
        split_bf16(a[j], hh, ll); h[j] = hh; l[j] = ll;
        split_bf16(b[j], hh, ll); h[4 + j] = hh; l[4 + j] = ll;
    }
    *(short8*)(Xh + idx) = h;
    *(short8*)(Xl + idx) = l;
}

// fp16 stream -> split-bf16 planes (exact: fp16 = bf16hi + bf16lo)
__global__ __launch_bounds__(256) void split_f16(const half_t* __restrict__ X,
                                                 short* __restrict__ Xh,
                                                 short* __restrict__ Xl) {
    size_t idx = ((size_t)blockIdx.x * 256 + threadIdx.x) * 8;
    half8 a = *(const half8*)(X + idx);
    short8 h, l;
    #pragma unroll
    for (int j = 0; j < 8; ++j) {
        short hh, ll;
        split_bf16((float)a[j], hh, ll); h[j] = hh; l[j] = ll;
    }
    *(short8*)(Xh + idx) = h;
    *(short8*)(Xl + idx) = l;
}

// C = A[M,K] @ Bt[N,K]^T with pre-split bf16 hi/lo planes for A and B.
// 128x128 tile, 4 waves (2x2), 4x4 16x16 frags/wave, 3-term MFMA, fp32 acc.
// Zero conversion VALU in the hot loop (split hoisted to prep kernels —
// r8's loop spent ~190 VALU/K-step on split_bf16 vs 48 MFMA).
// MODE 0: fp32 out at row*N+col (+ optional fp32 bias)
// MODE 1: fp16 out at row*2048 + (col>>6)*128 + (col&63)   (dpfp staging layout)
template <int MODE>
__global__ __launch_bounds__(256) void gemm_sb(const short* __restrict__ Ah,
                                               const short* __restrict__ Al,
                                               const short* __restrict__ Bh,
                                               const short* __restrict__ Bl,
                                               void* __restrict__ Cout,
                                               const float* __restrict__ bias,
                                               int N, int K) {
    __shared__ __align__(16) short As_h[128][40], As_l[128][40];   // 20 KB
    __shared__ __align__(16) short Bs_h[128][40], Bs_l[128][40];   // 20 KB
    const int tid  = threadIdx.x;
    const int wave = tid >> 6, lane = tid & 63;
    const int wr = wave >> 1, wc = wave & 1;       // 2x2 wave grid
    const int row0 = blockIdx.x * 128, col0 = blockIdx.y * 128;
    const int lr = tid >> 1, lc = (tid & 1) * 16;  // staging: 128 rows x 2 groups of 16
    const short* Aph = Ah + (size_t)(row0 + lr) * K + lc;
    const short* Apl = Al + (size_t)(row0 + lr) * K + lc;
    const short* Bph = Bh + (size_t)(col0 + lr) * K + lc;
    const short* Bpl = Bl + (size_t)(col0 + lr) * K + lc;
    const int fr = lane & 15;                      // frag row within 16
    const int ak = (lane >> 4) * 8;                // k-slice start
    floatx4 acc[4][4];
    #pragma unroll
    for (int m = 0; m < 4; ++m)
        #pragma unroll
        for (int n = 0; n < 4; ++n) acc[m][n] = (floatx4){0.f, 0.f, 0.f, 0.f};

    for (int k0 = 0; k0 < K; k0 += 32) {
        short8 vah0 = *(const short8*)(Aph + k0);
        short8 vah1 = *(const short8*)(Aph + k0 + 8);
        short8 val0 = *(const short8*)(Apl + k0);
        short8 val1 = *(const short8*)(Apl + k0 + 8);
        short8 vbh0 = *(const short8*)(Bph + k0);
        short8 vbh1 = *(const short8*)(Bph + k0 + 8);
        short8 vbl0 = *(const short8*)(Bpl + k0);
        short8 vbl1 = *(const short8*)(Bpl + k0 + 8);
        *(short8*)&As_h[lr][lc]     = vah0;
        *(short8*)&As_h[lr][lc + 8] = vah1;
        *(short8*)&As_l[lr][lc]     = val0;
        *(short8*)&As_l[lr][lc + 8] = val1;
        *(short8*)&Bs_h[lr][lc]     = vbh0;
        *(short8*)&Bs_h[lr][lc + 8] = vbh1;
        *(short8*)&Bs_l[lr][lc]     = vbl0;
        *(short8*)&Bs_l[lr][lc + 8] = vbl1;
        __syncthreads();

        short8 afh[4], afl[4], bfh[4], bfl[4];
        #pragma unroll
        for (int m = 0; m < 4; ++m) {
            afh[m] = *(const short8*)&As_h[wr * 64 + m * 16 + fr][ak];
            afl[m] = *(const short8*)&As_l[wr * 64 + m * 16 + fr][ak];
        }
        #pragma unroll
        for (int n = 0; n < 4; ++n) {
            bfh[n] = *(const short8*)&Bs_h[wc * 64 + n * 16 + fr][ak];
            bfl[n] = *(const short8*)&Bs_l[wc * 64 + n * 16 + fr][ak];
        }
        #pragma unroll
        for (int m = 0; m < 4; ++m)
            #pragma unroll
            for (int n = 0; n < 4; ++n) {
                acc[m][n] = __builtin_amdgcn_mfma_f32_16x16x32_bf16(afh[m], bfh[n], acc[m][n], 0, 0, 0);
                acc[m][n] = __builtin_amdgcn_mfma_f32_16x16x32_bf16(afh[m], bfl[n], acc[m][n], 0, 0, 0);
                acc[m][n] = __builtin_amdgcn_mfma_f32_16x16x32_bf16(afl[m], bfh[n], acc[m][n], 0, 0, 0);
            }
        __syncthreads();
    }
    // C/D layout (verified m89/m91): col = lane&15, row = (lane>>4)*4 + reg
    #pragma unroll
    for (int m = 0; m < 4; ++m) {
        const int crow = row0 + wr * 64 + m * 16 + (lane >> 4) * 4;
        #pragma unroll
        for (int n = 0; n < 4; ++n) {
            const int col = col0 + wc * 64 + n * 16 + (lane & 15);
            #pragma unroll
            for (int r = 0; r < 4; ++r) {
                int row = crow + r;
                float v = acc[m][n][r];
                if (MODE == 0) {
                    float bb = bias ? bias[col] : 0.f;
                    ((float*)Cout)[(size_t)row * N + col] = v + bb;
                } else {
                    ((half_t*)Cout)[(size_t)row * 2048 + (col >> 6) * 128 + (col & 63)] = (half_t)v;
                }
            }
        }
    }
}

// beta = sigmoid(x @ Wb); one wave per row, Wbt fp32 [16][1024]
__global__ __launch_bounds__(256) void beta_kernel(const float* __restrict__ X,
                                                   const float* __restrict__ Wbt,
                                                   float* __restrict__ Beta) {
    int wid  = (blockIdx.x * 256 + threadIdx.x) >> 6;
    int lane = threadIdx.x & 63;
    if (wid >= NROWS) return;
    const float* xr = X + (size_t)wid * DIM + lane * 16;
    float xv[16];
    #pragma unroll
    for (int j = 0; j < 4; ++j) {
        floatx4 v = *(const floatx4*)(xr + j * 4);
        #pragma unroll
        for (int e = 0; e < 4; ++e) xv[j * 4 + e] = v[e];
    }
    #pragma unroll 1
    for (int h = 0; h < 16; ++h) {
        const float* wr = Wbt + h * DIM + lane * 16;
        float s = 0.f;
        #pragma unroll
        for (int j = 0; j < 4; ++j) {
            floatx4 v = *(const floatx4*)(wr + j * 4);
            #pragma unroll
            for (int e = 0; e < 4; ++e) s = fmaf(xv[j * 4 + e], v[e], s);
        }
        #pragma unroll
        for (int off = 32; off; off >>= 1) s += __shfl_xor(s, off);
        if (lane == 0) Beta[wid * 16 + h] = 1.f / (1.f + __expf(-s));
    }
}

// In-place DPFP on fp16 spans of 128 (first 64 hold raw p, written by gemm MODE 1).
__global__ __launch_bounds__(256) void dpfp_h(half_t* __restrict__ P) {
    int gw   = (blockIdx.x * 256 + threadIdx.x) >> 6;
    int lane = threadIdx.x & 63;
    half_t* base = P + (size_t)gw * 128;
    float p  = (float)base[lane];
    float pm = __shfl(p, (lane + 63) & 63);           // p[lane-1], lane0 gets p[63]
    float rp  = fmaxf(p, 0.f),  rn  = fmaxf(-p, 0.f);
    float rpm = fmaxf(pm, 0.f), rnm = fmaxf(-pm, 0.f);
    float aprev = (lane == 0) ? rnm : rpm;            // xc[(lane-1)%128]
    float bprev = (lane == 0) ? rpm : rnm;            // xc[lane+63]
    float phi_a = rp * aprev;                         // phi[lane]
    float phi_b = rn * bprev;                         // phi[lane+64]
    float s = phi_a + phi_b;
    #pragma unroll
    for (int off = 32; off; off >>= 1) s += __shfl_xor(s, off);
    float inv = 1.f / (s + 1e-6f);
    base[lane]      = (half_t)(phi_a * inv);
    base[64 + lane] = (half_t)(phi_b * inv);
}

// ---- scan helpers: pair-lookahead (WY / delta-rule identity) ----
// Per pair of steps (even step E, odd step O), with w = state before the pair:
//   e0 = w.kE, e1 = w.kO, f0 = w.qE, f1 = w.qO   (4 independent reduces)
//   c0 = bE (vE - e0)
//   d1 = e1 + c0 * (kE.kO)            <- Gram scalar
//   c1 = bO (vO - d1)
//   y0 = f0 + c0 * (kE.qE)
//   y1 = f1 + c0 * (kE.qO) + c1 * (kO.qO)
//   w += c0 kE + c1 kO
// Gram scalars are row-independent -> precomputed once per chunk in LDS.
// (r7 lesson: depth-4 lookahead blows the register budget (136 VGPR) and the
// scheduler serializes the reduce chains — depth 2 is the local optimum.)

#define LOADSTEP(DK, DQ, STEP)                                              \
    {                                                                       \
        floatx4 _ka = *(const floatx4*)&Ks[bufi][STEP][tc * 8];             \
        floatx4 _kb = *(const floatx4*)&Ks[bufi][STEP][tc * 8 + 4];         \
        floatx4 _qa = *(const floatx4*)&Qs[bufi][STEP][tc * 8];             \
        floatx4 _qb = *(const floatx4*)&Qs[bufi][STEP][tc * 8 + 4];         \
        for (int _i = 0; _i < 4; ++_i) {                                    \
            DK[_i] = _ka[_i]; DK[4 + _i] = _kb[_i];                         \
            DQ[_i] = _qa[_i]; DQ[4 + _i] = _qb[_i];                         \
        }                                                                   \
    }

#define DOT8(RES, X, Y)                                                     \
    {                                                                       \
        float _s0 = X[0] * Y[0], _s1 = X[1] * Y[1];                         \
        _s0 = fmaf(X[2], Y[2], _s0); _s1 = fmaf(X[3], Y[3], _s1);           \
        _s0 = fmaf(X[4], Y[4], _s0); _s1 = fmaf(X[5], Y[5], _s1);           \
        _s0 = fmaf(X[6], Y[6], _s0); _s1 = fmaf(X[7], Y[7], _s1);           \
        RES = _s0 + _s1;                                                    \
    }

// One pair: prefetch pair P+1 into the N* register set, 4 dots+reduces on C*,
// tiny serial part, batched w update, y stores.
#define PAIR(CEK, CEQ, COK, COQ, CEV, CEB, COV, COB, CG,                    \
             NEK, NEQ, NOK, NOQ, NEV, NEB, NOV, NOB, NG, P)                 \
    {                                                                       \
        if ((P) + 1 < 16) {                                                 \
            LOADSTEP(NEK, NEQ, 2 * (P) + 2);                                \
            LOADSTEP(NOK, NOQ, 2 * (P) + 3);                                \
            NEV = Vs[bufi][2 * (P) + 2][row_l];                             \
            NEB = Bs[bufi][2 * (P) + 2];                                    \
            NOV = Vs[bufi][2 * (P) + 3][row_l];                             \
            NOB = Bs[bufi][2 * (P) + 3];                                    \
            NG  = *(const floatx4*)&GramLDS[(P) + 1][0];                    \
        }                                                                   \
        float _e0, _e1, _f0, _f1;                                           \
        DOT8(_e0, w, CEK); DOT8(_e1, w, COK);                               \
        DOT8(_f0, w, CEQ); DOT8(_f1, w, COQ);                               \
        _e0 = row16_allreduce(_e0); _e1 = row16_allreduce(_e1);             \
        _f0 = row16_allreduce(_f0); _f1 = row16_allreduce(_f1);             \
        float _c0 = CEB * (CEV - _e0);                                      \
        float _d1 = fmaf(_c0, CG[0], _e1);                                  \
        float _c1 = COB * (COV - _d1);                                      \
        float _y0 = fmaf(_c0, CG[1], _f0);                                  \
        float _y1 = fmaf(_c1, CG[3], fmaf(_c0, CG[2], _f1));                \
        for (int _j = 0; _j < 8; ++_j)                                      \
            w[_j] = fmaf(_c1, COK[_j], fmaf(_c0, CEK[_j], w[_j]));          \
        if (tc == 0) {                                                      \
            ybase[(size_t)((cc * CHUNK + 2 * (P))     * BATCH + b) * 1024] = (half_t)_y0; \
            ybase[(size_t)((cc * CHUNK + 2 * (P) + 1) * BATCH + b) * 1024] = (half_t)_y1; \
        }                                                                   \
    }

// Sequential fast-weight scan, r0 geometry (proven): 256 blocks = 64 bh x 4
// row-chunks of 16 rows; 16 lanes/row, 8 fp32 state/lane; chunk staging with
// double-buffered LDS + register-held global prefetch.  Pair-lookahead inner
// loop (measured 660 us): the ~470-cyc dep chain is paid once per 2 steps and
// the pair's 4 reduces pipeline.
__global__ __launch_bounds__(256, 1) void scan_kernel(const half_t* __restrict__ PhiK,
                                                      const half_t* __restrict__ PhiQ,
                                                      const float* __restrict__ V,
                                                      const float* __restrict__ Beta,
                                                      half_t* __restrict__ Y) {
    __shared__ float Ks[2][CHUNK][128];   // 32 KB
    __shared__ float Qs[2][CHUNK][128];   // 32 KB
    __shared__ float Vs[2][CHUNK][16];    //  4 KB
    __shared__ float Bs[2][CHUNK];        // 256 B
    __shared__ float GramLDS[16][4];      // 256 B: per pair {kE.kO, kE.qE, kE.qO, kO.qO}

    const int bh = blockIdx.x >> 2;     // 0..63
    const int rc = blockIdx.x & 3;      // row chunk
    const int b = bh >> 4, h = bh & 15;
    const int tid = threadIdx.x;
    const int row_l = tid >> 4;         // 0..15
    const int tc = tid & 15;            // column group (8 floats)
    const int vrow = rc * 16 + row_l;   // 0..63

    const half_t* kg = PhiK + h * 128;
    const half_t* qg = PhiQ + h * 128;
    const float*  vg = V + h * 64 + rc * 16;
    const float*  bg = Beta + h;
    half_t* ybase = Y + h * 64 + vrow;

    // ---- stage chunk 0 directly ----
    {
        #pragma unroll
        for (int rpt = 0; rpt < 2; ++rpt) {
            int i = rpt * 256 + tid;              // 0..511
            int st = i >> 4, seg = i & 15, row = i & 15;
            size_t r = (size_t)(st * BATCH + b);
            half8 kv = *(const half8*)(kg + r * 2048 + seg * 8);
            half8 qv = *(const half8*)(qg + r * 2048 + seg * 8);
            floatx4 klo, khi, qlo, qhi;
            #pragma unroll
            for (int j = 0; j < 4; ++j) {
                klo[j] = (float)kv[j]; khi[j] = (float)kv[4 + j];
                qlo[j] = (float)qv[j]; qhi[j] = (float)qv[4 + j];
            }
            *(floatx4*)&Ks[0][st][seg * 8]     = klo;
            *(floatx4*)&Ks[0][st][seg * 8 + 4] = khi;
            *(floatx4*)&Qs[0][st][seg * 8]     = qlo;
            *(floatx4*)&Qs[0][st][seg * 8 + 4] = qhi;
            Vs[0][st][row] = vg[r * 1024 + row];
        }
        if (tid < CHUNK) {
            size_t r = (size_t)(tid * BATCH + b);
            Bs[0][tid] = bg[r * 16];
        }
    }
    __syncthreads();

    float w[8];
    #pragma unroll
    for (int j = 0; j < 8; ++j) w[j] = 0.f;

    for (int cc = 0; cc < NCHUNK; ++cc) {
        const int bufi = cc & 1;
        const bool more = (cc + 1 < NCHUNK);

        // ---- Gram precompute for chunk cc: row-group g handles pair g ----
        {
            float ka[8], kb[8], qa[8], qb[8];
            LOADSTEP(ka, qa, 2 * row_l);
            LOADSTEP(kb, qb, 2 * row_l + 1);
            float skk, s00, s01, s11;
            DOT8(skk, ka, kb);
            DOT8(s00, ka, qa);
            DOT8(s01, ka, qb);
            DOT8(s11, kb, qb);
            skk = row16_allreduce(skk);
            s00 = row16_allreduce(s00);
            s01 = row16_allreduce(s01);
            s11 = row16_allreduce(s11);
            if (tc == 0) {
                GramLDS[row_l][0] = skk;
                GramLDS[row_l][1] = s00;
                GramLDS[row_l][2] = s01;
                GramLDS[row_l][3] = s11;
            }
        }
        __syncthreads();   // Gram visible (LDS-only traffic -> cheap drain)

        // ---- issue global loads for chunk cc+1 (held in regs until after compute) ----
        half8 pk[2], pq[2];
        float pv[2], pb = 0.f;
        if (more) {
            #pragma unroll
            for (int rpt = 0; rpt < 2; ++rpt) {
                int i = rpt * 256 + tid;
                int st = i >> 4, seg = i & 15, row = i & 15;
                size_t r = (size_t)(((cc + 1) * CHUNK + st) * BATCH + b);
                pk[rpt] = *(const half8*)(kg + r * 2048 + seg * 8);
                pq[rpt] = *(const half8*)(qg + r * 2048 + seg * 8);
                pv[rpt] = vg[r * 1024 + row];
            }
            if (tid < CHUNK) {
                size_t r = (size_t)(((cc + 1) * CHUNK + tid) * BATCH + b);
                pb = bg[r * 16];
            }
        }

        // ---- preload pair 0 (set 0) ----
        float EK0[8], EQ0[8], OK0[8], OQ0[8];
        float EK1[8], EQ1[8], OK1[8], OQ1[8];
        float Ev0, Eb0, Ov0, Ob0, Ev1, Eb1, Ov1, Ob1;
        floatx4 G0, G1;
        LOADSTEP(EK0, EQ0, 0);
        LOADSTEP(OK0, OQ0, 1);
        Ev0 = Vs[bufi][0][row_l]; Eb0 = Bs[bufi][0];
        Ov0 = Vs[bufi][1][row_l]; Ob0 = Bs[bufi][1];
        G0 = *(const floatx4*)&GramLDS[0][0];

        // ---- 16 pairs, ping-pong register sets ----
        #pragma unroll 1
        for (int p2 = 0; p2 < 16; p2 += 2) {
            PAIR(EK0, EQ0, OK0, OQ0, Ev0, Eb0, Ov0, Ob0, G0,
                 EK1, EQ1, OK1, OQ1, Ev1, Eb1, Ov1, Ob1, G1, p2);
            PAIR(EK1, EQ1, OK1, OQ1, Ev1, Eb1, Ov1, Ob1, G1,
                 EK0, EQ0, OK0, OQ0, Ev0, Eb0, Ov0, Ob0, G0, p2 + 1);
        }

        // ---- write staged chunk cc+1 into the other buffer ----
        if (more) {
            const int bufn = bufi ^ 1;
            #pragma unroll
            for (int rpt = 0; rpt < 2; ++rpt) {
                int i = rpt * 256 + tid;
                int st = i >> 4, seg = i & 15, row = i & 15;
                floatx4 klo, khi, qlo, qhi;
                #pragma unroll
                for (int j = 0; j < 4; ++j) {
                    klo[j] = (float)pk[rpt][j]; khi[j] = (float)pk[rpt][4 + j];
                    qlo[j] = (float)pq[rpt][j]; qhi[j] = (float)pq[rpt][4 + j];
                }
                *(floatx4*)&Ks[bufn][st][seg * 8]     = klo;
                *(floatx4*)&Ks[bufn][st][seg * 8 + 4] = khi;
                *(floatx4*)&Qs[bufn][st][seg * 8]     = qlo;
                *(floatx4*)&Qs[bufn][st][seg * 8 + 4] = qhi;
                Vs[bufn][st][row] = pv[rpt];
            }
            if (tid < CHUNK) Bs[bufn][tid] = pb;
        }
        __syncthreads();
    }
}

extern "C" void kernel_launch(void* const* d_in, const int* in_sizes, int n_in,
                              void* d_out, int out_size, void* d_ws, size_t ws_size,
                              hipStream_t stream) {
    const float* x  = (const float*)d_in[0];
    const float* Wq = (const float*)d_in[1];
    const float* Wk = (const float*)d_in[2];
    const float* Wv = (const float*)d_in[3];
    const float* Wb = (const float*)d_in[4];
    const float* Wo = (const float*)d_in[5];
    const float* bo = (const float*)d_in[6];

    char* ws = (char*)d_ws;
    size_t off = 0;
    auto alloc = [&](size_t bytes) -> void* {
        void* p = ws + off;
        off += (bytes + 255) & ~(size_t)255;
        return p;
    };
    half_t* PhiQ = (half_t*)alloc((size_t)NROWS * 2048 * 2);  // 64 MB
    half_t* PhiK = (half_t*)alloc((size_t)NROWS * 2048 * 2);  // 64 MB
    half_t* Yb   = (half_t*)alloc((size_t)NROWS * 1024 * 2);  // 32 MB
    float*  Beta = (float*)alloc((size_t)NROWS * 16 * 4);     //  1 MB
    short*  Xh   = (short*)alloc((size_t)NROWS * 1024 * 2);   // 32 MB (reused for Yh)
    short*  Xl   = (short*)alloc((size_t)NROWS * 1024 * 2);   // 32 MB (reused for Yl)
    short*  Wqh  = (short*)alloc((size_t)1024 * 1024 * 2);    //  2 MB each
    short*  Wql  = (short*)alloc((size_t)1024 * 1024 * 2);
    short*  Wkh  = (short*)alloc((size_t)1024 * 1024 * 2);
    short*  Wkl  = (short*)alloc((size_t)1024 * 1024 * 2);
    short*  Wvh  = (short*)alloc((size_t)1024 * 1024 * 2);
    short*  Wvl  = (short*)alloc((size_t)1024 * 1024 * 2);
    short*  Woh  = (short*)alloc((size_t)1024 * 1024 * 2);
    short*  Wol  = (short*)alloc((size_t)1024 * 1024 * 2);
    float*  Wbt  = (float*)alloc((size_t)16 * 1024 * 4);
    float*  Vb   = (float*)d_out;  // V staged in d_out (fp32, dead before final GEMM)

    transpose_split<<<4096, 256, 0, stream>>>(Wq, Wqh, Wql, 1024, 1024);
    transpose_split<<<4096, 256, 0, stream>>>(Wk, Wkh, Wkl, 1024, 1024);
    transpose_split<<<4096, 256, 0, stream>>>(Wv, Wvh, Wvl, 1024, 1024);
    transpose_split<<<4096, 256, 0, stream>>>(Wo, Woh, Wol, 1024, 1024);
    transpose_k<<<64, 256, 0, stream>>>(Wb, Wbt, 1024, 16);
    split_f32<<<8192, 256, 0, stream>>>(x, Xh, Xl);   // 16384*1024 / 2048

    dim3 ggrid(NROWS / 128, DIM / 128);
    const int dgrid = (NROWS * 16) / 4;
    gemm_sb<1><<<ggrid, 256, 0, stream>>>(Xh, Xl, Wqh, Wql, PhiQ, nullptr, DIM, DIM);
    dpfp_h<<<dgrid, 256, 0, stream>>>(PhiQ);
    gemm_sb<1><<<ggrid, 256, 0, stream>>>(Xh, Xl, Wkh, Wkl, PhiK, nullptr, DIM, DIM);
    dpfp_h<<<dgrid, 256, 0, stream>>>(PhiK);
    gemm_sb<0><<<ggrid, 256, 0, stream>>>(Xh, Xl, Wvh, Wvl, Vb, nullptr, DIM, DIM);
    beta_kernel<<<NROWS / 4, 256, 0, stream>>>(x, Wbt, Beta);
    scan_kernel<<<256, 256, 0, stream>>>(PhiK, PhiQ, Vb, Beta, Yb);
    // x consumers are done; reuse Xh/Xl for the split of Yb
    split_f16<<<8192, 256, 0, stream>>>(Yb, Xh, Xl);
    gemm_sb<0><<<ggrid, 256, 0, stream>>>(Xh, Xl, Woh, Wol, d_out, bo, DIM, DIM);
}